// Round 2
// baseline (345.213 us; speedup 1.0000x reference)
//
#include <hip/hip_runtime.h>

// MoE SwiGLU gather, bf16 MFMA grouped GEMM. R5: TLP attack.
// Counters (R4): occ 29% = grid-limited (~460 active blocks, 1.4/CU);
// all pipes idle -> latency stalls exposed with nothing else resident.
//  - h/d tile 64->32: 2x active blocks (weight HBM traffic unchanged).
//  - A operand back in LDS (coalesced staging, dbuf) -> no per-chunk
//    gather wait in front of the MFMA cluster.
//  - waves 4m x 2n (32x16 per wave), depth-2 reg prefetch, lgkm-only
//    barriers (loads stay in flight across s_barrier).

#define NEXP 8
#define HDIM 2816
#define DDIM 1024
#define NPAIR 1024

typedef unsigned int uint;
typedef unsigned short ushort;
typedef __attribute__((ext_vector_type(8))) short bf16x8;
typedef __attribute__((ext_vector_type(4))) float fvec4;
typedef __attribute__((ext_vector_type(4))) uint uvec4;

__device__ __forceinline__ ushort f2bf(float f) {
    uint u = __builtin_bit_cast(uint, f);
    u += 0x7fff + ((u >> 16) & 1);          // RTNE
    return (ushort)(u >> 16);
}
__device__ __forceinline__ uint pack2(float lo, float hi) {
    return (uint)f2bf(lo) | ((uint)f2bf(hi) << 16);
}
__device__ __forceinline__ uvec4 pack8(fvec4 a, fvec4 b) {
    uvec4 v;
    v.x = pack2(a.x, a.y); v.y = pack2(a.z, a.w);
    v.z = pack2(b.x, b.y); v.w = pack2(b.z, b.w);
    return v;
}

// LDS-only workgroup barrier: drains DS ops but leaves global loads in
// flight (vs __syncthreads' vmcnt(0) drain).
__device__ __forceinline__ void wg_sync_lds() {
    __builtin_amdgcn_sched_barrier(0);
    asm volatile("s_waitcnt lgkmcnt(0)" ::: "memory");
    __builtin_amdgcn_s_barrier();
    __builtin_amdgcn_sched_barrier(0);
}

// ws: [0] counts 32B | [1024] lists 32KB | [65536] hbuf bf16 5.77MB
__global__ __launch_bounds__(1024) void route_kernel(const int* __restrict__ idx,
                                                     int* __restrict__ counts,
                                                     int* __restrict__ lists) {
    int p = threadIdx.x;
    if (p < NEXP) counts[p] = 0;     // ws re-poisoned every call
    __syncthreads();
    int e = idx[p];
    int pos = atomicAdd(&counts[e], 1);
    lists[e * NPAIR + pos] = p;
}

#define LDK 68                 // 64 + 4 ushort pad (2-way bank alias only)

// ---------------- Phase 1: hbuf[p,h] = silu(x·w1)*(x·w3) ----------------
// grid (8, 88, 8) = (expert, 32-h tile, 128-m tile), block 512 (8 waves
// as 4m x 2h; wave tile 32m x 16h, both mats). K-chunk 64, 16 chunks.
#define NCH1 (DDIM / 64)       // 16

__global__ __launch_bounds__(512, 4) void h_mfma(const float* __restrict__ x,
                       const float* __restrict__ w1,
                       const float* __restrict__ w3,
                       const int* __restrict__ counts,
                       const int* __restrict__ lists,
                       ushort* __restrict__ hb) {
    const int e = blockIdx.x;
    const int cnt = counts[e];
    const int m0 = blockIdx.z * 128;
    if (m0 >= cnt) return;
    const int h0 = blockIdx.y * 32;

    __shared__ ushort sA[2][128 * LDK];
    __shared__ ushort sB[2][2][32 * LDK];   // [buf][mat][h*LDK+k]
    __shared__ int sTok[128];
    __shared__ int sPairS[128];

    const int tid = threadIdx.x;
    if (tid < 128) {
        int m = m0 + tid;
        int mc = (m < cnt) ? m : (cnt - 1);
        int p = lists[e * NPAIR + mc];
        sTok[tid] = p >> 1;                 // TOPK=2
        sPairS[tid] = (m < cnt) ? p : -1;
    }
    wg_sync_lds();

    // staging roles: A: 4 thr/row x 16 floats (64B contiguous);
    //                B: 8 thr/row x 8 floats, mat = tid>>8.
    const int arow = tid >> 2;
    const int akg  = (tid & 3) * 16;
    const float* aSrc = x + (size_t)sTok[arow] * DDIM + akg;

    const int bmat = tid >> 8;
    const int brow = (tid >> 3) & 31;
    const int bkg  = (tid & 7) * 8;
    const float* bSrc = (bmat ? w3 : w1) + (size_t)e * HDIM * DDIM
                        + (size_t)(h0 + brow) * DDIM + bkg;

    fvec4 pfA[2][4];
    fvec4 pfB[2][2];

#define P1_ISSUE(S, KC) do { \
    const float* qa = aSrc + (KC) * 64; \
    pfA[S][0] = *(const fvec4*)qa; \
    pfA[S][1] = *(const fvec4*)(qa + 4); \
    pfA[S][2] = *(const fvec4*)(qa + 8); \
    pfA[S][3] = *(const fvec4*)(qa + 12); \
    const float* qb = bSrc + (KC) * 64; \
    pfB[S][0] = *(const fvec4*)qb; \
    pfB[S][1] = *(const fvec4*)(qb + 4); \
} while (0)

#define P1_STAGE(S, B) do { \
    *(uvec4*)&sA[B][arow * LDK + akg] = pack8(pfA[S][0], pfA[S][1]); \
    *(uvec4*)&sA[B][arow * LDK + akg + 8] = pack8(pfA[S][2], pfA[S][3]); \
    *(uvec4*)&sB[B][bmat][brow * LDK + bkg] = pack8(pfB[S][0], pfB[S][1]); \
} while (0)

    const int w = tid >> 6;
    const int wm = w & 3;                   // m quarter (32 rows)
    const int wh = w >> 2;                  // h half (16 cols)
    const int lane = tid & 63;
    const int l16 = lane & 15;
    const int quad = lane >> 4;

    const int ar0 = (wm * 32 + l16) * LDK + quad * 8;   // mi=0; +16*LDK mi=1; +32 kh=1
    const int br0 = (wh * 16 + l16) * LDK + quad * 8;

    fvec4 acc[2][2];   // [mi][mat]
    #pragma unroll
    for (int i = 0; i < 2; ++i) { acc[i][0] = (fvec4)0.f; acc[i][1] = (fvec4)0.f; }

    P1_ISSUE(0, 0);
    P1_ISSUE(1, 1);
    P1_STAGE(0, 0);        // compiler waits set0 only (vmcnt counted)
    wg_sync_lds();

    // iter T (CUR=T&1): buf CUR = chunk T; pf[CUR^1] = chunk T+1 (in
    // flight); issue chunk T+2 into pf[CUR]. Stage-wait is vmcnt(6).
#define P1_BODY(T, CUR) do { \
    bf16x8 a00 = *(const bf16x8*)&sA[CUR][ar0]; \
    bf16x8 a01 = *(const bf16x8*)&sA[CUR][ar0 + 32]; \
    bf16x8 a10 = *(const bf16x8*)&sA[CUR][ar0 + 16 * LDK]; \
    bf16x8 a11 = *(const bf16x8*)&sA[CUR][ar0 + 16 * LDK + 32]; \
    bf16x8 b00 = *(const bf16x8*)&sB[CUR][0][br0]; \
    bf16x8 b01 = *(const bf16x8*)&sB[CUR][0][br0 + 32]; \
    bf16x8 b10 = *(const bf16x8*)&sB[CUR][1][br0]; \
    bf16x8 b11 = *(const bf16x8*)&sB[CUR][1][br0 + 32]; \
    if ((T) + 2 < NCH1) P1_ISSUE(CUR, (T) + 2); \
    acc[0][0] = __builtin_amdgcn_mfma_f32_16x16x32_bf16(a00, b00, acc[0][0], 0, 0, 0); \
    acc[0][1] = __builtin_amdgcn_mfma_f32_16x16x32_bf16(a00, b10, acc[0][1], 0, 0, 0); \
    acc[1][0] = __builtin_amdgcn_mfma_f32_16x16x32_bf16(a10, b00, acc[1][0], 0, 0, 0); \
    acc[1][1] = __builtin_amdgcn_mfma_f32_16x16x32_bf16(a10, b10, acc[1][1], 0, 0, 0); \
    acc[0][0] = __builtin_amdgcn_mfma_f32_16x16x32_bf16(a01, b01, acc[0][0], 0, 0, 0); \
    acc[0][1] = __builtin_amdgcn_mfma_f32_16x16x32_bf16(a01, b11, acc[0][1], 0, 0, 0); \
    acc[1][0] = __builtin_amdgcn_mfma_f32_16x16x32_bf16(a11, b01, acc[1][0], 0, 0, 0); \
    acc[1][1] = __builtin_amdgcn_mfma_f32_16x16x32_bf16(a11, b11, acc[1][1], 0, 0, 0); \
    if ((T) + 1 < NCH1) { \
        P1_STAGE(CUR ^ 1, CUR ^ 1); \
        wg_sync_lds(); \
    } \
} while (0)

    for (int t = 0; t < NCH1; t += 2) {     // 16, even
        P1_BODY(t, 0);
        P1_BODY(t + 1, 1);
    }

    // epilogue: C/D col=l16, row=quad*4+r
    #pragma unroll
    for (int mi = 0; mi < 2; ++mi) {
        #pragma unroll
        for (int r = 0; r < 4; ++r) {
            int mrow = wm * 32 + mi * 16 + quad * 4 + r;
            int p = sPairS[mrow];
            if (p >= 0) {
                float a = acc[mi][0][r];
                float g = acc[mi][1][r];
                float s = a / (1.f + __expf(-a)) * g;
                hb[(size_t)p * HDIM + h0 + wh * 16 + l16] = f2bf(s);
            }
        }
    }
}

// ---------------- Phase 2: out[p,d] += hbuf[p,:]·w2[e,:,d] ----------------
// grid (8, 32, 32): (expert, 32-d tile, mblock*4 + splitK). block 512,
// waves 4m x 2d. K-chunk 64, 11 chunks per split, fp32 atomic reduce.
#define NCH2 ((HDIM / 4) / 64)   // 11

__global__ __launch_bounds__(512, 4) void out_mfma(const float* __restrict__ w2,
                         const int* __restrict__ counts,
                         const int* __restrict__ lists,
                         const ushort* __restrict__ hb,
                         float* __restrict__ out) {
    const int e = blockIdx.x;
    const int cnt = counts[e];
    const int mb = blockIdx.z >> 2;
    const int sk = blockIdx.z & 3;
    const int m0 = mb * 128;
    if (m0 >= cnt) return;
    const int n0 = blockIdx.y * 32;
    const int kbase = sk * (HDIM / 4);      // 704 per split

    __shared__ ushort sA[2][128 * LDK];
    __shared__ ushort sB[2][32 * LDK];      // [buf][d*LDK+k]
    __shared__ int sPairC[128];
    __shared__ int sPairS[128];

    const int tid = threadIdx.x;
    if (tid < 128) {
        int m = m0 + tid;
        int mc = (m < cnt) ? m : (cnt - 1);
        int p = lists[e * NPAIR + mc];
        sPairC[tid] = p;
        sPairS[tid] = (m < cnt) ? p : -1;
    }
    wg_sync_lds();

    // A: bf16 copy from hbuf, 4 thr/row x 32B. B: w2 transpose-stage,
    // threads 0..255: 2 k-rows x 4 d-floats each, pack2 -> 4B writes.
    const int arow = tid >> 2;
    const int akg  = (tid & 3) * 16;        // ushort offset
    const ushort* aSrc = hb + (size_t)sPairC[arow] * HDIM + kbase + akg;

    const int bkp = (tid >> 3) & 31;        // k pair 0..31
    const int bdg = tid & 7;                // d group (4 floats)
    const float* bSrc = w2 + (size_t)e * HDIM * DDIM
                        + (size_t)(kbase + 2 * bkp) * DDIM + n0 + bdg * 4;

    uvec4 pfA[2][2];
    fvec4 pfB[2][2];

#define P2_ISSUE(S, KC) do { \
    const ushort* qa = aSrc + (KC) * 64; \
    pfA[S][0] = *(const uvec4*)qa; \
    pfA[S][1] = *(const uvec4*)(qa + 8); \
    if (tid < 256) { \
        const float* qb = bSrc + (size_t)(KC) * 64 * DDIM; \
        pfB[S][0] = *(const fvec4*)qb; \
        pfB[S][1] = *(const fvec4*)(qb + DDIM); \
    } \
} while (0)

#define P2_STAGE(S, B) do { \
    *(uvec4*)&sA[B][arow * LDK + akg] = pfA[S][0]; \
    *(uvec4*)&sA[B][arow * LDK + akg + 8] = pfA[S][1]; \
    if (tid < 256) { \
        _Pragma("unroll") \
        for (int j = 0; j < 4; ++j) \
            *(uint*)&sB[B][(bdg * 4 + j) * LDK + bkp * 2] = pack2(pfB[S][0][j], pfB[S][1][j]); \
    } \
} while (0)

    const int w = tid >> 6;
    const int wm = w & 3;
    const int wh = w >> 2;
    const int lane = tid & 63;
    const int l16 = lane & 15;
    const int quad = lane >> 4;

    const int ar0 = (wm * 32 + l16) * LDK + quad * 8;
    const int br0 = (wh * 16 + l16) * LDK + quad * 8;

    fvec4 acc[2];
    acc[0] = (fvec4)0.f; acc[1] = (fvec4)0.f;

    P2_ISSUE(0, 0);
    P2_ISSUE(1, 1);
    P2_STAGE(0, 0);
    wg_sync_lds();

#define P2_BODY(T, CUR) do { \
    bf16x8 a00 = *(const bf16x8*)&sA[CUR][ar0]; \
    bf16x8 a01 = *(const bf16x8*)&sA[CUR][ar0 + 32]; \
    bf16x8 a10 = *(const bf16x8*)&sA[CUR][ar0 + 16 * LDK]; \
    bf16x8 a11 = *(const bf16x8*)&sA[CUR][ar0 + 16 * LDK + 32]; \
    bf16x8 b0 = *(const bf16x8*)&sB[CUR][br0]; \
    bf16x8 b1 = *(const bf16x8*)&sB[CUR][br0 + 32]; \
    if ((T) + 2 < NCH2) P2_ISSUE(CUR, (T) + 2); \
    acc[0] = __builtin_amdgcn_mfma_f32_16x16x32_bf16(a00, b0, acc[0], 0, 0, 0); \
    acc[1] = __builtin_amdgcn_mfma_f32_16x16x32_bf16(a10, b0, acc[1], 0, 0, 0); \
    acc[0] = __builtin_amdgcn_mfma_f32_16x16x32_bf16(a01, b1, acc[0], 0, 0, 0); \
    acc[1] = __builtin_amdgcn_mfma_f32_16x16x32_bf16(a11, b1, acc[1], 0, 0, 0); \
    if ((T) + 1 < NCH2) { \
        P2_STAGE(CUR ^ 1, CUR ^ 1); \
        wg_sync_lds(); \
    } \
} while (0)

    for (int t = 0; t < NCH2; t += 2) {     // 11, odd
        P2_BODY(t, 0);
        if (t + 1 < NCH2) P2_BODY(t + 1, 1);
    }

    #pragma unroll
    for (int mi = 0; mi < 2; ++mi) {
        #pragma unroll
        for (int r = 0; r < 4; ++r) {
            int mrow = wm * 32 + mi * 16 + quad * 4 + r;
            int p = sPairS[mrow];
            if (p >= 0)
                atomicAdd(&out[(size_t)p * DDIM + n0 + wh * 16 + l16], acc[mi][r]);
        }
    }
}

extern "C" void kernel_launch(void* const* d_in, const int* in_sizes, int n_in,
                              void* d_out, int out_size, void* d_ws, size_t ws_size,
                              hipStream_t stream) {
    const float* x   = (const float*)d_in[0];
    const int*   idx = (const int*)d_in[1];
    const float* w1  = (const float*)d_in[2];
    const float* w2  = (const float*)d_in[3];
    const float* w3  = (const float*)d_in[4];
    float* out = (float*)d_out;

    char* ws = (char*)d_ws;
    int*    counts = (int*)ws;
    int*    lists  = (int*)(ws + 1024);
    ushort* hbuf   = (ushort*)(ws + 65536);

    hipMemsetAsync(out, 0, (size_t)out_size * sizeof(float), stream);
    route_kernel<<<1, NPAIR, 0, stream>>>(idx, counts, lists);
    h_mfma<<<dim3(NEXP, HDIM / 32, NPAIR / 128), 512, 0, stream>>>(
        x, w1, w3, counts, lists, hbuf);
    out_mfma<<<dim3(NEXP, DDIM / 32, (NPAIR / 128) * 4), 512, 0, stream>>>(
        w2, counts, lists, hbuf, out);
}